// Round 2
// baseline (45.122 us; speedup 1.0000x reference)
//
#include <hip/hip_runtime.h>
#include <math.h>

#define B_ 8
#define C_ 512
#define T_ 64
#define W_ 14
#define H_ 14
#define N_ 3
#define EPSF 1e-6f
#define WH (W_*H_)          /* 196 */
#define TWH (T_*W_*H_)      /* 12544 */
#define NF4 (TWH/4)         /* 3136 */

// Kernel 1: compute separable weights.
//   wt[b][n][t]  = exp(-0.5*pt*(t-mu_tb)^2) / (Z[b,n] + EPS)   (norm folded in)
//   wxy[n][w*H+h] = exp(-0.5*(px*(w-mx)^2 + py*(h-my)^2))
__global__ void TSF_weights_kernel(const float* __restrict__ length,
                                   const float* __restrict__ mu_t,
                                   const float* __restrict__ mu_x,
                                   const float* __restrict__ mu_y,
                                   const float* __restrict__ sigma_t,
                                   const float* __restrict__ sigma_x,
                                   const float* __restrict__ sigma_y,
                                   float* __restrict__ wt,    // [B][N][T]
                                   float* __restrict__ wxy)   // [N][WH]
{
    __shared__ float s_wxy[N_][WH];
    __shared__ float s_ft[B_][N_][T_];
    __shared__ float s_sxy[N_];
    __shared__ float s_st[B_][N_];
    const int tid = threadIdx.x;

    // spatial weights (N*196 = 588 entries)
    for (int i = tid; i < N_*WH; i += blockDim.x) {
        int n = i / WH;
        int r = i - n*WH;
        int w = r / H_;
        int h = r - w*H_;
        float sx = expf(1.5f - 2.0f*fabsf(tanhf(sigma_x[n])));
        float sy = expf(1.5f - 2.0f*fabsf(tanhf(sigma_y[n])));
        float px = 1.0f/(sx*sx + EPSF);
        float py = 1.0f/(sy*sy + EPSF);
        float mx = (float)(W_-1) * (tanhf(mu_x[n]) + 1.0f) * 0.5f;
        float my = (float)(H_-1) * (tanhf(mu_y[n]) + 1.0f) * 0.5f;
        float dx = (float)w - mx;
        float dy = (float)h - my;
        s_wxy[n][r] = expf(-0.5f*(px*dx*dx + py*dy*dy));
    }
    // temporal weights (B*N*T = 1536 entries)
    for (int i = tid; i < B_*N_*T_; i += blockDim.x) {
        int b  = i / (N_*T_);
        int rm = i - b*(N_*T_);
        int n  = rm / T_;
        int t  = rm - n*T_;
        float st = expf(1.5f - 2.0f*fabsf(tanhf(sigma_t[n])));
        float pt = 1.0f/(st*st + EPSF);
        float mt = (length[b] - 1.0f) * (tanhf(mu_t[n]) + 1.0f) * 0.5f;
        float d  = (float)t - mt;
        s_ft[b][n][t] = expf(-0.5f*pt*d*d);
    }
    __syncthreads();

    if (tid < N_) {
        float s = 0.f;
        for (int r = 0; r < WH; ++r) s += s_wxy[tid][r];
        s_sxy[tid] = s;
    }
    if (tid >= 32 && tid < 32 + B_*N_) {
        int i = tid - 32;
        int b = i / N_, n = i - b*N_;
        float s = 0.f;
        for (int t = 0; t < T_; ++t) s += s_ft[b][n][t];
        s_st[b][n] = s;
    }
    __syncthreads();

    for (int i = tid; i < N_*WH; i += blockDim.x)
        wxy[i] = (&s_wxy[0][0])[i];
    for (int i = tid; i < B_*N_*T_; i += blockDim.x) {
        int b  = i / (N_*T_);
        int rm = i - b*(N_*T_);
        int n  = rm / T_;
        float Z = s_st[b][n] * s_sxy[n];
        wt[i] = (&s_ft[0][0][0])[i] * (1.0f/(Z + EPSF));
    }
}

// Kernel 2: one block per (b,c). Stream 12544 contiguous fp32 (float4), weight
// by wt[t]*wxy[r..r+3], accumulate 3 partials per thread, block-reduce.
__global__ __launch_bounds__(256) void TSF_pool_kernel(
        const float* __restrict__ video,
        const float* __restrict__ wt,
        const float* __restrict__ wxy,
        float* __restrict__ out)
{
    const int bc = blockIdx.x;        // b*C + c
    const int b  = bc >> 9;           // C_ = 512
    const int tid = threadIdx.x;

    __shared__ float s_wt[N_][T_];
    __shared__ float s_wxy[N_][WH];   // rows are 784 B = 49*16 B -> 16B aligned
    for (int i = tid; i < N_*T_;  i += 256) (&s_wt[0][0])[i]  = wt[b*N_*T_ + i];
    for (int i = tid; i < N_*WH; i += 256) (&s_wxy[0][0])[i] = wxy[i];
    __syncthreads();

    const float4* vp = (const float4*)(video + (size_t)bc * TWH);
    float a0 = 0.f, a1 = 0.f, a2 = 0.f;
    for (int p = tid; p < NF4; p += 256) {
        float4 v = vp[p];
        int e = p << 2;
        int t = e / WH;               // magic-mul div by 196
        int r = e - t*WH;             // r % 4 == 0 since 196 % 4 == 0
        float4 w0 = *(const float4*)&s_wxy[0][r];
        float4 w1 = *(const float4*)&s_wxy[1][r];
        float4 w2 = *(const float4*)&s_wxy[2][r];
        float d0 = v.x*w0.x + v.y*w0.y + v.z*w0.z + v.w*w0.w;
        float d1 = v.x*w1.x + v.y*w1.y + v.z*w1.z + v.w*w1.w;
        float d2 = v.x*w2.x + v.y*w2.y + v.z*w2.z + v.w*w2.w;
        a0 += s_wt[0][t]*d0;
        a1 += s_wt[1][t]*d1;
        a2 += s_wt[2][t]*d2;
    }

    // wave(64) shuffle reduce
    for (int off = 32; off > 0; off >>= 1) {
        a0 += __shfl_down(a0, off, 64);
        a1 += __shfl_down(a1, off, 64);
        a2 += __shfl_down(a2, off, 64);
    }
    __shared__ float s_red[4][N_];
    const int wave = tid >> 6;
    if ((tid & 63) == 0) {
        s_red[wave][0] = a0; s_red[wave][1] = a1; s_red[wave][2] = a2;
    }
    __syncthreads();
    if (tid < N_) {
        float s = s_red[0][tid] + s_red[1][tid] + s_red[2][tid] + s_red[3][tid];
        out[(size_t)bc * N_ + tid] = s;   // out[b][c*N + n]
    }
}

extern "C" void kernel_launch(void* const* d_in, const int* in_sizes, int n_in,
                              void* d_out, int out_size, void* d_ws, size_t ws_size,
                              hipStream_t stream) {
    const float* video   = (const float*)d_in[0];
    const float* length  = (const float*)d_in[1];
    const float* mu_t    = (const float*)d_in[2];
    const float* mu_x    = (const float*)d_in[3];
    const float* mu_y    = (const float*)d_in[4];
    const float* sigma_t = (const float*)d_in[5];
    const float* sigma_x = (const float*)d_in[6];
    const float* sigma_y = (const float*)d_in[7];

    float* wt  = (float*)d_ws;          // B*N*T = 1536 floats
    float* wxy = wt + B_*N_*T_;         // N*WH  = 588 floats

    TSF_weights_kernel<<<1, 256, 0, stream>>>(length, mu_t, mu_x, mu_y,
                                              sigma_t, sigma_x, sigma_y, wt, wxy);
    TSF_pool_kernel<<<B_*C_, 256, 0, stream>>>(video, wt, wxy, (float*)d_out);
}

// Round 3
// 38.349 us; speedup vs baseline: 1.1766x; 1.1766x over previous
//
#include <hip/hip_runtime.h>
#include <math.h>

#define B_ 8
#define C_ 512
#define T_ 64
#define W_ 14
#define H_ 14
#define N_ 3
#define EPSF 1e-6f
#define WH (W_*H_)          /* 196 */
#define TWH (T_*W_*H_)      /* 12544 */
#define NF4 (TWH/4)         /* 3136 */

// Single fused kernel: one block per (b,c).
// Phase 1: waves 0..2 each compute Gaussian n=w's weights:
//   ft[t]  = exp(-0.5*pt*(t-mu_tb)^2)            (t = lane, exactly 64)
//   wxy[r] = exp(-0.5*(px*dx^2 + py*dy^2))        (r lane-strided over 196)
//   Z = (sum ft)*(sum wxy);  s_wt[n][t] = ft[t] / (Z + EPS)
// Phase 2: stream the block's contiguous 12544-float video chunk as float4,
//   accumulate 3 weighted sums, block-reduce, write 3 outputs.
__global__ __launch_bounds__(256) void TSF_fused_kernel(
        const float* __restrict__ video,
        const float* __restrict__ length,
        const float* __restrict__ mu_t,
        const float* __restrict__ mu_x,
        const float* __restrict__ mu_y,
        const float* __restrict__ sigma_t,
        const float* __restrict__ sigma_x,
        const float* __restrict__ sigma_y,
        float* __restrict__ out)
{
    const int bc  = blockIdx.x;       // b*C + c
    const int b   = bc >> 9;          // C_ = 512
    const int tid = threadIdx.x;
    const int wave = tid >> 6;
    const int lane = tid & 63;

    __shared__ float s_wt[N_][T_];
    __shared__ float s_wxy[N_][WH];   // rows are 784 B = 49*16 B -> 16B aligned

    if (wave < N_) {
        const int n = wave;
        // scalar transforms (redundant across lanes — cheap)
        float st = expf(1.5f - 2.0f*fabsf(tanhf(sigma_t[n])));
        float sx = expf(1.5f - 2.0f*fabsf(tanhf(sigma_x[n])));
        float sy = expf(1.5f - 2.0f*fabsf(tanhf(sigma_y[n])));
        float pt = 1.0f/(st*st + EPSF);
        float px = 1.0f/(sx*sx + EPSF);
        float py = 1.0f/(sy*sy + EPSF);
        float mt = (length[b] - 1.0f) * (tanhf(mu_t[n]) + 1.0f) * 0.5f;
        float mx = (float)(W_-1) * (tanhf(mu_x[n]) + 1.0f) * 0.5f;
        float my = (float)(H_-1) * (tanhf(mu_y[n]) + 1.0f) * 0.5f;

        // temporal: lane == t
        float dtv = (float)lane - mt;
        float ftv = expf(-0.5f*pt*dtv*dtv);
        float sft = ftv;
        #pragma unroll
        for (int off = 1; off < 64; off <<= 1)
            sft += __shfl_xor(sft, off, 64);

        // spatial: r = lane, lane+64, lane+128, lane+192(<196)
        float swxy = 0.f;
        #pragma unroll
        for (int k = 0; k < 4; ++k) {
            int r = lane + 64*k;
            if (r < WH) {
                int w = r / H_;
                int h = r - w*H_;
                float dx = (float)w - mx;
                float dy = (float)h - my;
                float v = expf(-0.5f*(px*dx*dx + py*dy*dy));
                s_wxy[n][r] = v;
                swxy += v;
            }
        }
        #pragma unroll
        for (int off = 1; off < 64; off <<= 1)
            swxy += __shfl_xor(swxy, off, 64);

        float norm = 1.0f / (sft*swxy + EPSF);
        s_wt[n][lane] = ftv * norm;
    }
    __syncthreads();

    // Phase 2: stream video
    const float4* vp = (const float4*)(video + (size_t)bc * TWH);
    float a0 = 0.f, a1 = 0.f, a2 = 0.f;
    for (int p = tid; p < NF4; p += 256) {
        float4 v = vp[p];
        int e = p << 2;
        int t = e / WH;               // magic-mul div by 196
        int r = e - t*WH;             // r % 4 == 0 since 196 % 4 == 0
        float4 w0 = *(const float4*)&s_wxy[0][r];
        float4 w1 = *(const float4*)&s_wxy[1][r];
        float4 w2 = *(const float4*)&s_wxy[2][r];
        float d0 = v.x*w0.x + v.y*w0.y + v.z*w0.z + v.w*w0.w;
        float d1 = v.x*w1.x + v.y*w1.y + v.z*w1.z + v.w*w1.w;
        float d2 = v.x*w2.x + v.y*w2.y + v.z*w2.z + v.w*w2.w;
        a0 += s_wt[0][t]*d0;
        a1 += s_wt[1][t]*d1;
        a2 += s_wt[2][t]*d2;
    }

    // wave(64) shuffle reduce
    #pragma unroll
    for (int off = 32; off > 0; off >>= 1) {
        a0 += __shfl_down(a0, off, 64);
        a1 += __shfl_down(a1, off, 64);
        a2 += __shfl_down(a2, off, 64);
    }
    __shared__ float s_red[4][N_];
    if (lane == 0) {
        s_red[wave][0] = a0; s_red[wave][1] = a1; s_red[wave][2] = a2;
    }
    __syncthreads();
    if (tid < N_) {
        float s = s_red[0][tid] + s_red[1][tid] + s_red[2][tid] + s_red[3][tid];
        out[(size_t)bc * N_ + tid] = s;   // out[b][c*N + n]
    }
}

extern "C" void kernel_launch(void* const* d_in, const int* in_sizes, int n_in,
                              void* d_out, int out_size, void* d_ws, size_t ws_size,
                              hipStream_t stream) {
    const float* video   = (const float*)d_in[0];
    const float* length  = (const float*)d_in[1];
    const float* mu_t    = (const float*)d_in[2];
    const float* mu_x    = (const float*)d_in[3];
    const float* mu_y    = (const float*)d_in[4];
    const float* sigma_t = (const float*)d_in[5];
    const float* sigma_x = (const float*)d_in[6];
    const float* sigma_y = (const float*)d_in[7];

    TSF_fused_kernel<<<B_*C_, 256, 0, stream>>>(video, length, mu_t, mu_x, mu_y,
                                                sigma_t, sigma_x, sigma_y,
                                                (float*)d_out);
}